// Round 3
// baseline (347.850 us; speedup 1.0000x reference)
//
#include <hip/hip_runtime.h>
#include <hip/hip_bf16.h>

// Round 11: software-pipeline the attention K/V loads (register double-buffer,
// depth 1). Round-10 counters showed the loop is latency-bound: MFMA 10% +
// VALU 30% busy, ~60% idle at 14 waves/CU — each j-step issued 8 reg loads
// and consumed them immediately (vmcnt(0) every step, ~500cy L2/L3 latency
// exposed). Now step t+1's loads are issued before step t's compute, so the
// compiler waits at vmcnt(8) and the latency hides under ~220cy of compute.
// Buffers are statically named (aK0/vf0, aK1/vf1), pipeline loop unrolled x2
// (rule #20: no runtime-indexed reg arrays). Everything else frozen (r10).
// ws: [8 counters @128B = 1KB] | xb[8M] | wab[3M] | wpb[1M] | Q[8M] | K[8M] | Vt[8M] | O[8M]

typedef __hip_bfloat16 bf16;
typedef __attribute__((ext_vector_type(8))) short bf16x8;   // 8 bf16 / 4 VGPRs
typedef __attribute__((ext_vector_type(4))) float f32x4;
typedef __attribute__((ext_vector_type(16))) float f32x16;

#define MFMA16(a, b, c) __builtin_amdgcn_mfma_f32_16x16x32_bf16(a, b, c, 0, 0, 0)
#define MFMA32(a, b, c) __builtin_amdgcn_mfma_f32_32x32x16_bf16(a, b, c, 0, 0, 0)
#define GLOAD_LDS(g, l) __builtin_amdgcn_global_load_lds( \
    (const __attribute__((address_space(1))) void*)(g),    \
    (__attribute__((address_space(3))) void*)(l), 16, 0, 0)

constexpr int Bn = 4, Tn = 2048, Cn = 1024, Hn = 16, Dn = 64;
constexpr size_t HT_ELEMS = (size_t)64 * Tn * Dn;   // 8388608
constexpr float QSCALE = 0.18033688011112042f;      // 0.125 * log2(e)
constexpr int OSTRIDE = 36;                         // obuf row stride (floats)

__device__ __forceinline__ short f2bf(float f) {    // RNE fp32->bf16 (finite)
    unsigned u = __float_as_uint(f);
    return (short)((u + 0x7FFF + ((u >> 16) & 1)) >> 16);
}
__device__ __forceinline__ bf16 bfbits(short s) { bf16 b; __builtin_memcpy(&b, &s, 2); return b; }

__device__ __forceinline__ unsigned cvtpk_bf16(float lo, float hi) {
    unsigned r;
    asm("v_cvt_pk_bf16_f32 %0, %1, %2" : "=v"(r) : "v"(lo), "v"(hi));
    return r;
}
// swap(a,b): a' = {a_lo, b_lo}, b' = {a_hi, b_hi}  (32-lane halves)
__device__ __forceinline__ void permswap(unsigned& a, unsigned& b) {
#if __has_builtin(__builtin_amdgcn_permlane32_swap)
    auto r = __builtin_amdgcn_permlane32_swap(a, b, false, false);
    a = (unsigned)r[0]; b = (unsigned)r[1];
#else
    asm("v_permlane32_swap_b32 %0, %1" : "+v"(a), "+v"(b));
#endif
}
__device__ __forceinline__ bf16x8 pack4(unsigned w0, unsigned w1, unsigned w2, unsigned w3) {
    union { unsigned u[4]; bf16x8 v; } t;
    t.u[0] = w0; t.u[1] = w1; t.u[2] = w2; t.u[3] = w3;
    return t.v;
}

// ---------------- fp32 -> bf16 cast, all three inputs in one launch -------
// Output region xb|wab|wpb is contiguous; segment-select the input.
// Units of 8 elems: x 1048576 | w_attn 393216 | w_proj 131072 (total 1572864).
__global__ __launch_bounds__(256) void cast3_kernel(
    const float* __restrict__ x, const float* __restrict__ wa,
    const float* __restrict__ wp, bf16* __restrict__ out)
{
    size_t i = (size_t)blockIdx.x * 256 + threadIdx.x;
    const float* src; size_t off;
    if (i < 1048576)      { src = x;  off = i; }
    else if (i < 1441792) { src = wa; off = i - 1048576; }
    else                  { src = wp; off = i - 1441792; }
    const float4* p = (const float4*)(src + off * 8);
    float4 a = p[0], b = p[1];
    bf16x8 r;
    r[0] = f2bf(a.x); r[1] = f2bf(a.y); r[2] = f2bf(a.z); r[3] = f2bf(a.w);
    r[4] = f2bf(b.x); r[5] = f2bf(b.y); r[6] = f2bf(b.z); r[7] = f2bf(b.w);
    *(bf16x8*)(out + i * 8) = r;
}

// ---------------- QKV GEMM: 128x128 tile, LDS-staged (m97 pattern) --------
__global__ __launch_bounds__(256) void qkv_gemm128(
    const bf16* __restrict__ Am, const bf16* __restrict__ Wm,
    const float* __restrict__ bias,
    bf16* __restrict__ qo, bf16* __restrict__ ko, bf16* __restrict__ vo)
{
    constexpr int K = 1024;
    __shared__ bf16 As[4096], Bs[4096];          // 128 rows x 32 k, stride 32
    const int tid = threadIdx.x;
    const int lane = tid & 63, w = tid >> 6;
    const int row = lane & 15, quad = lane >> 4;
    const int tn = blockIdx.x % 24, tm = blockIdx.x / 24;
    const int m0 = tm * 128, n0 = tn * 128;

    const int srow = tid >> 2, skch = tid & 3;   // staging: 4 threads/row (64B)
    const bf16* ag0 = Am + (size_t)(m0 + srow) * K + skch * 8;
    const bf16* ag1 = ag0 + (size_t)64 * K;
    const bf16* wg0 = Wm + (size_t)(n0 + srow) * K + skch * 8;
    const bf16* wg1 = wg0 + (size_t)64 * K;
    bf16* asl0 = As + tid * 8;  bf16* asl1 = As + 2048 + tid * 8;
    bf16* bsl0 = Bs + tid * 8;  bf16* bsl1 = Bs + 2048 + tid * 8;

    f32x4 acc[4][4];
    #pragma unroll
    for (int i = 0; i < 4; i++)
        #pragma unroll
        for (int j = 0; j < 4; j++) acc[i][j] = {0, 0, 0, 0};

    const int r0 = (w >> 1) * 64, c0 = (w & 1) * 64;

    for (int k0 = 0; k0 < K; k0 += 32) {
        __syncthreads();
        GLOAD_LDS(ag0 + k0, asl0);
        GLOAD_LDS(ag1 + k0, asl1);
        GLOAD_LDS(wg0 + k0, bsl0);
        GLOAD_LDS(wg1 + k0, bsl1);
        __syncthreads();
        bf16x8 af[4], bfv[4];
        #pragma unroll
        for (int it = 0; it < 4; it++)
            af[it] = *(const bf16x8*)(As + (r0 + it * 16 + row) * 32 + quad * 8);
        #pragma unroll
        for (int jt = 0; jt < 4; jt++)
            bfv[jt] = *(const bf16x8*)(Bs + (c0 + jt * 16 + row) * 32 + quad * 8);
        #pragma unroll
        for (int it = 0; it < 4; it++)
            #pragma unroll
            for (int jt = 0; jt < 4; jt++)
                acc[it][jt] = MFMA16(af[it], bfv[jt], acc[it][jt]);
    }

    #pragma unroll
    for (int it = 0; it < 4; it++)
    #pragma unroll
    for (int jt = 0; jt < 4; jt++)
    #pragma unroll
    for (int r = 0; r < 4; r++) {
        int m = m0 + r0 + it * 16 + quad * 4 + r;
        int n = n0 + c0 + jt * 16 + row;
        float val = acc[it][jt][r] + bias[n];
        int which = n >> 10, cc = n & 1023;
        if (which == 0) val *= QSCALE;
        bf16 bv = bfbits(f2bf(val));
        int h = cc >> 6, d = cc & 63;
        int b = m >> 11, t = m & 2047;
        int bh = b * Hn + h;
        if (which == 0)      qo[((size_t)bh * Tn + t) * Dn + d] = bv;
        else if (which == 1) ko[((size_t)bh * Tn + t) * Dn + d] = bv;
        else                 vo[((size_t)bh * Dn + d) * Tn + t] = bv;
    }
}

// ---------------- Attention: per-XCD queue + block-level k-split ----------
// Item = (bh, 32-query tile). Block's 4 waves split key-blocks j=w,w+4,...
// Per j-step (32 keys x 32 queries), all in registers:
//   S^T = K*Q^T via 4x mfma_32x32x16 (rows=keys, cols=queries, lane owns
//   query l31); exp2 -> p[16] f32; lsum = f32 add-tree; P packed to bf16 via
//   v_cvt_pk_bf16_f32 and half-wave-swapped via permlane32_swap into the PV
//   A-fragment layout; PV = 4x mfma_32x32x16.
// K/V loads are double-buffered one step ahead (issue-early / consume-late).
__global__ __launch_bounds__(256, 3) void attn_kernel(
    const bf16* __restrict__ qb, const bf16* __restrict__ kb,
    const bf16* __restrict__ vtb, bf16* __restrict__ ob,
    unsigned* __restrict__ counters)
{
    __shared__ float obuf[64][OSTRIDE];         // 9 KB: merge buffer [d][q]
    __shared__ float lbuf[32];
    __shared__ unsigned item_s;
    const int tid  = threadIdx.x;
    const int lane = tid & 63;
    const int w    = tid >> 6;
    const int l31  = lane & 31, hl = lane >> 5;
    const int qid = blockIdx.x & 7;             // round-robin XCD heuristic
    unsigned* ctr = counters + qid * 32;        // 128B apart

    for (;;) {
        if (tid == 0) item_s = atomicAdd(ctr, 1u);
        __syncthreads();
        const unsigned item = item_s;
        if (item >= 512u) break;
        const int qt = 63 - (int)(item >> 3);   // LPT: longest first
        const int bh = qid * 8 + (int)(item & 7);
        const int q0 = qt * 32;

        const bf16* Q  = qb  + (size_t)bh * Tn * Dn;
        const bf16* Kp = kb  + (size_t)bh * Tn * Dn;
        const bf16* Vt = vtb + (size_t)bh * Dn * Tn;

        // Q fragments: B-operand of S^T, B[k=d][col=query l31]
        bf16x8 bQ[4];
        {
            const bf16* qp = Q + (size_t)(q0 + l31) * Dn + hl * 8;
            #pragma unroll
            for (int kf = 0; kf < 4; kf++) bQ[kf] = *(const bf16x8*)(qp + kf * 16);
        }

        f32x16 o2[2];
        o2[0] = {0,0,0,0,0,0,0,0,0,0,0,0,0,0,0,0};
        o2[1] = {0,0,0,0,0,0,0,0,0,0,0,0,0,0,0,0};
        float lsum = 0.f;

        // this wave's key-blocks: j = w, w+4, ... <= qt  (ns steps)
        const int ns = (qt >= w) ? (((qt - w) >> 2) + 1) : 0;
        bf16x8 aK0[4], vf0[4], aK1[4], vf1[4];

#define LOADKV(A, V, jj) do {                                              \
        const int kk0_ = (jj) * 32;                                        \
        const bf16* kp_ = Kp + (size_t)(kk0_ + l31) * Dn + hl * 8;         \
        A[0] = *(const bf16x8*)(kp_);                                      \
        A[1] = *(const bf16x8*)(kp_ + 16);                                 \
        A[2] = *(const bf16x8*)(kp_ + 32);                                 \
        A[3] = *(const bf16x8*)(kp_ + 48);                                 \
        const bf16* vp_ = Vt + (size_t)l31 * Tn + kk0_ + hl * 8;           \
        V[0] = *(const bf16x8*)(vp_);                                      \
        V[1] = *(const bf16x8*)(vp_ + 16);                                 \
        V[2] = *(const bf16x8*)(vp_ + (size_t)32 * Tn);                    \
        V[3] = *(const bf16x8*)(vp_ + (size_t)32 * Tn + 16);               \
    } while (0)

#define STEP(A, V, jj) do {                                                \
        f32x16 s_ = {0,0,0,0,0,0,0,0,0,0,0,0,0,0,0,0};                    \
        __builtin_amdgcn_s_setprio(1);                                     \
        s_ = MFMA32(A[0], bQ[0], s_);                                      \
        s_ = MFMA32(A[1], bQ[1], s_);                                      \
        s_ = MFMA32(A[2], bQ[2], s_);                                      \
        s_ = MFMA32(A[3], bQ[3], s_);                                      \
        __builtin_amdgcn_s_setprio(0);                                     \
        float p_[16];                                                      \
        if ((jj) == qt) {            /* diagonal block: causal mask */     \
            _Pragma("unroll")                                              \
            for (int r_ = 0; r_ < 16; r_++) {                              \
                const int krow_ = (r_ & 3) + 8 * (r_ >> 2) + 4 * hl;       \
                float e_ = exp2f(s_[r_]);                                  \
                p_[r_] = (krow_ > l31) ? 0.f : e_;                         \
            }                                                              \
        } else {                                                           \
            _Pragma("unroll")                                              \
            for (int r_ = 0; r_ < 16; r_++) p_[r_] = exp2f(s_[r_]);        \
        }                                                                  \
        lsum += (((p_[0]+p_[1]) + (p_[2]+p_[3]))                           \
               + ((p_[4]+p_[5]) + (p_[6]+p_[7])))                          \
              + (((p_[8]+p_[9]) + (p_[10]+p_[11]))                         \
               + ((p_[12]+p_[13]) + (p_[14]+p_[15])));                     \
        unsigned a0_ = cvtpk_bf16(p_[0],  p_[1]),  b0_ = cvtpk_bf16(p_[4],  p_[5]);  \
        unsigned a1_ = cvtpk_bf16(p_[2],  p_[3]),  b1_ = cvtpk_bf16(p_[6],  p_[7]);  \
        unsigned a2_ = cvtpk_bf16(p_[8],  p_[9]),  b2_ = cvtpk_bf16(p_[12], p_[13]); \
        unsigned a3_ = cvtpk_bf16(p_[10], p_[11]), b3_ = cvtpk_bf16(p_[14], p_[15]); \
        permswap(a0_, b0_);                                                \
        permswap(a1_, b1_);                                                \
        permswap(a2_, b2_);                                                \
        permswap(a3_, b3_);                                                \
        const bf16x8 P0_ = pack4(a0_, a1_, b0_, b1_);   /* keys 0..15 */   \
        const bf16x8 P1_ = pack4(a2_, a3_, b2_, b3_);   /* keys 16..31 */  \
        __builtin_amdgcn_s_setprio(1);                                     \
        o2[0] = MFMA32(P0_, V[0], o2[0]);                                  \
        o2[0] = MFMA32(P1_, V[1], o2[0]);                                  \
        o2[1] = MFMA32(P0_, V[2], o2[1]);                                  \
        o2[1] = MFMA32(P1_, V[3], o2[1]);                                  \
        __builtin_amdgcn_s_setprio(0);                                     \
    } while (0)

        if (ns > 0) {
            LOADKV(aK0, vf0, w);
            int j0 = w, t = 0;
            while (t + 2 <= ns) {
                LOADKV(aK1, vf1, j0 + 4);
                STEP(aK0, vf0, j0);
                if (t + 2 < ns) LOADKV(aK0, vf0, j0 + 8);
                STEP(aK1, vf1, j0 + 4);
                t += 2; j0 += 8;
            }
            if (t < ns) STEP(aK0, vf0, j0);
        }
#undef LOADKV
#undef STEP

        // lsum partner-sum across hl halves (all lanes end with full q-sum)
        unsigned lsu = __float_as_uint(lsum), lsv = lsu;
        permswap(lsu, lsv);
        const float ltot = __uint_as_float(lsu) + __uint_as_float(lsv);

        // ---- merge partials: obuf[d][q] (+ lbuf[q]), waves 3->0 ----
        __syncthreads();
        #pragma unroll
        for (int ww = 3; ww >= 0; ww--) {
            if (w == ww) {
                #pragma unroll
                for (int nt = 0; nt < 2; nt++)
                    #pragma unroll
                    for (int g = 0; g < 4; g++) {
                        // o2[nt][g*4+rr]: query = rr + 8*g + 4*hl, d = nt*32+l31
                        float* dst = &obuf[nt * 32 + l31][g * 8 + hl * 4];
                        f32x4 vv = { o2[nt][g*4+0], o2[nt][g*4+1],
                                     o2[nt][g*4+2], o2[nt][g*4+3] };
                        if (ww != 3) { f32x4 old = *(f32x4*)dst; vv += old; }
                        *(f32x4*)dst = vv;
                    }
                if (hl == 0) {
                    if (ww == 3) lbuf[l31] = ltot;
                    else         lbuf[l31] += ltot;
                }
            }
            __syncthreads();
        }

        // ---- final write: 256 threads, 8 d-elems each ----
        {
            const int q = tid >> 3, dblk = (tid & 7) * 8;
            const float rcp = 1.0f / lbuf[q];
            bf16x8 rv;
            #pragma unroll
            for (int d = 0; d < 8; d++)
                rv[d] = f2bf(obuf[dblk + d][q] * rcp);
            const int b = bh >> 4, h = bh & 15;
            const int t = q0 + q;
            *(bf16x8*)(ob + ((size_t)(b * Tn + t)) * Cn + h * Dn + dblk) = rv;
        }
        __syncthreads();   // obuf/lbuf/item_s reuse guard
    }
}

// ---------------- Output projection: 128x128 tile, fp32 out ---------------
__global__ __launch_bounds__(256) void proj_gemm128(
    const bf16* __restrict__ Am, const bf16* __restrict__ Wm,
    const float* __restrict__ bias, float* __restrict__ out)
{
    constexpr int K = 1024;
    __shared__ bf16 As[4096], Bs[4096];
    const int tid = threadIdx.x;
    const int lane = tid & 63, w = tid >> 6;
    const int row = lane & 15, quad = lane >> 4;
    const int tn = blockIdx.x % 8, tm = blockIdx.x / 8;
    const int m0 = tm * 128, n0 = tn * 128;

    const int srow = tid >> 2, skch = tid & 3;
    const bf16* ag0 = Am + (size_t)(m0 + srow) * K + skch * 8;
    const bf16* ag1 = ag0 + (size_t)64 * K;
    const bf16* wg0 = Wm + (size_t)(n0 + srow) * K + skch * 8;
    const bf16* wg1 = wg0 + (size_t)64 * K;
    bf16* asl0 = As + tid * 8;  bf16* asl1 = As + 2048 + tid * 8;
    bf16* bsl0 = Bs + tid * 8;  bf16* bsl1 = Bs + 2048 + tid * 8;

    f32x4 acc[4][4];
    #pragma unroll
    for (int i = 0; i < 4; i++)
        #pragma unroll
        for (int j = 0; j < 4; j++) acc[i][j] = {0, 0, 0, 0};

    const int r0 = (w >> 1) * 64, c0 = (w & 1) * 64;

    for (int k0 = 0; k0 < K; k0 += 32) {
        __syncthreads();
        GLOAD_LDS(ag0 + k0, asl0);
        GLOAD_LDS(ag1 + k0, asl1);
        GLOAD_LDS(wg0 + k0, bsl0);
        GLOAD_LDS(wg1 + k0, bsl1);
        __syncthreads();
        bf16x8 af[4], bfv[4];
        #pragma unroll
        for (int it = 0; it < 4; it++)
            af[it] = *(const bf16x8*)(As + (r0 + it * 16 + row) * 32 + quad * 8);
        #pragma unroll
        for (int jt = 0; jt < 4; jt++)
            bfv[jt] = *(const bf16x8*)(Bs + (c0 + jt * 16 + row) * 32 + quad * 8);
        #pragma unroll
        for (int it = 0; it < 4; it++)
            #pragma unroll
            for (int jt = 0; jt < 4; jt++)
                acc[it][jt] = MFMA16(af[it], bfv[jt], acc[it][jt]);
    }

    #pragma unroll
    for (int it = 0; it < 4; it++)
    #pragma unroll
    for (int jt = 0; jt < 4; jt++)
    #pragma unroll
    for (int r = 0; r < 4; r++) {
        int m = m0 + r0 + it * 16 + quad * 4 + r;
        int n = n0 + c0 + jt * 16 + row;
        out[(size_t)m * 1024 + n] = acc[it][jt][r] + bias[n];
    }
}

extern "C" void kernel_launch(void* const* d_in, const int* in_sizes, int n_in,
                              void* d_out, int out_size, void* d_ws, size_t ws_size,
                              hipStream_t stream) {
    const float* x      = (const float*)d_in[0];
    const float* w_attn = (const float*)d_in[1];
    const float* b_attn = (const float*)d_in[2];
    const float* w_proj = (const float*)d_in[3];
    const float* b_proj = (const float*)d_in[4];
    float* out = (float*)d_out;

    unsigned* counters = (unsigned*)d_ws;             // 8 counters @128B
    bf16* ws  = (bf16*)((char*)d_ws + 1024);
    bf16* xb  = ws;                                   // 8M elems
    bf16* wab = xb  + (size_t)8192 * 1024;            // 3M (contiguous after xb)
    bf16* wpb = wab + (size_t)3072 * 1024;            // 1M (contiguous after wab)
    bf16* q   = wpb + (size_t)1024 * 1024;            // 8M
    bf16* k   = q  + HT_ELEMS;
    bf16* vt  = k  + HT_ELEMS;
    bf16* o   = vt + HT_ELEMS;

    hipMemsetAsync(counters, 0, 1024, stream);

    cast3_kernel<<<6144, 256, 0, stream>>>(x, w_attn, w_proj, xb);

    qkv_gemm128 <<<64 * 24, 256, 0, stream>>>(xb, wab, b_attn, q, k, vt);
    attn_kernel <<<2048, 256, 0, stream>>>(q, k, vt, o, counters);
    proj_gemm128<<<64 * 8, 256, 0, stream>>>(o, wpb, b_proj, out);
}

// Round 4
// 304.728 us; speedup vs baseline: 1.1415x; 1.1415x over previous
//
#include <hip/hip_runtime.h>
#include <hip/hip_bf16.h>

// Round 12: attention restructured around shared-key-block LDS staging.
// r10/r11 evidence: per-wave register K/V loads are lane=row strided -> each
// global_load_dwordx4 scatters into 32 cache lines (256 line-requests per
// wave-step) -> ~2000cy effective step latency, SIMDs ~90% idle; r11's reg
// double-buffer spilled (WRITE_SIZE 16.6->46.7MB) and changed nothing.
// New structure: item = (bh, 128-query block); 4 waves each own 32 queries
// and iterate the SAME key-block j. K(4KB)+V(4KB) tiles staged per block
// (traffic /4) via 8 coalesced global_load_lds, LDS double-buffered, 2-phase
// (stage j+1 || compute j, one barrier per step). Tiles stored with
// chunk^=stripe&7 XOR swizzle via pre-swizzled global source (rule #21);
// ds_read_b128 fragments ~4-way instead of 16-32-way conflicted. V layout in
// qkv_gemm changed to [bh][kblock][d64][k32] so V tiles are contiguous.
// Cross-wave merge DELETED (each wave owns its queries end-to-end); epilogue
// is a per-wave LDS transpose reusing the staging buffer -> coalesced stores.
// S^T/softmax/permlane/PV lane math identical to r10 (harness-verified).
// ws: [8 counters @128B = 1KB] | xb[8M] | wab[3M] | wpb[1M] | Q[8M] | K[8M] | Vt[8M] | O[8M]

typedef __hip_bfloat16 bf16;
typedef __attribute__((ext_vector_type(8))) short bf16x8;   // 8 bf16 / 4 VGPRs
typedef __attribute__((ext_vector_type(4))) float f32x4;
typedef __attribute__((ext_vector_type(16))) float f32x16;

#define MFMA16(a, b, c) __builtin_amdgcn_mfma_f32_16x16x32_bf16(a, b, c, 0, 0, 0)
#define MFMA32(a, b, c) __builtin_amdgcn_mfma_f32_32x32x16_bf16(a, b, c, 0, 0, 0)
#define GLOAD_LDS(g, l) __builtin_amdgcn_global_load_lds( \
    (const __attribute__((address_space(1))) void*)(g),    \
    (__attribute__((address_space(3))) void*)(l), 16, 0, 0)

constexpr int Bn = 4, Tn = 2048, Cn = 1024, Hn = 16, Dn = 64;
constexpr size_t HT_ELEMS = (size_t)64 * Tn * Dn;   // 8388608
constexpr float QSCALE = 0.18033688011112042f;      // 0.125 * log2(e)

__device__ __forceinline__ short f2bf(float f) {    // RNE fp32->bf16 (finite)
    unsigned u = __float_as_uint(f);
    return (short)((u + 0x7FFF + ((u >> 16) & 1)) >> 16);
}
__device__ __forceinline__ bf16 bfbits(short s) { bf16 b; __builtin_memcpy(&b, &s, 2); return b; }

__device__ __forceinline__ unsigned cvtpk_bf16(float lo, float hi) {
    unsigned r;
    asm("v_cvt_pk_bf16_f32 %0, %1, %2" : "=v"(r) : "v"(lo), "v"(hi));
    return r;
}
// swap(a,b): a' = {a_lo, b_lo}, b' = {a_hi, b_hi}  (32-lane halves)
__device__ __forceinline__ void permswap(unsigned& a, unsigned& b) {
#if __has_builtin(__builtin_amdgcn_permlane32_swap)
    auto r = __builtin_amdgcn_permlane32_swap(a, b, false, false);
    a = (unsigned)r[0]; b = (unsigned)r[1];
#else
    asm("v_permlane32_swap_b32 %0, %1" : "+v"(a), "+v"(b));
#endif
}
__device__ __forceinline__ bf16x8 pack4(unsigned w0, unsigned w1, unsigned w2, unsigned w3) {
    union { unsigned u[4]; bf16x8 v; } t;
    t.u[0] = w0; t.u[1] = w1; t.u[2] = w2; t.u[3] = w3;
    return t.v;
}

// ---------------- fp32 -> bf16 cast, all three inputs in one launch -------
__global__ __launch_bounds__(256) void cast3_kernel(
    const float* __restrict__ x, const float* __restrict__ wa,
    const float* __restrict__ wp, bf16* __restrict__ out)
{
    size_t i = (size_t)blockIdx.x * 256 + threadIdx.x;
    const float* src; size_t off;
    if (i < 1048576)      { src = x;  off = i; }
    else if (i < 1441792) { src = wa; off = i - 1048576; }
    else                  { src = wp; off = i - 1441792; }
    const float4* p = (const float4*)(src + off * 8);
    float4 a = p[0], b = p[1];
    bf16x8 r;
    r[0] = f2bf(a.x); r[1] = f2bf(a.y); r[2] = f2bf(a.z); r[3] = f2bf(a.w);
    r[4] = f2bf(b.x); r[5] = f2bf(b.y); r[6] = f2bf(b.z); r[7] = f2bf(b.w);
    *(bf16x8*)(out + i * 8) = r;
}

// ---------------- QKV GEMM: 128x128 tile, LDS-staged (m97 pattern) --------
// V output layout: [bh][kblock=t>>5][d=64][tk=t&31]  (contiguous 4KB tiles)
__global__ __launch_bounds__(256) void qkv_gemm128(
    const bf16* __restrict__ Am, const bf16* __restrict__ Wm,
    const float* __restrict__ bias,
    bf16* __restrict__ qo, bf16* __restrict__ ko, bf16* __restrict__ vo)
{
    constexpr int K = 1024;
    __shared__ bf16 As[4096], Bs[4096];          // 128 rows x 32 k, stride 32
    const int tid = threadIdx.x;
    const int lane = tid & 63, w = tid >> 6;
    const int row = lane & 15, quad = lane >> 4;
    const int tn = blockIdx.x % 24, tm = blockIdx.x / 24;
    const int m0 = tm * 128, n0 = tn * 128;

    const int srow = tid >> 2, skch = tid & 3;   // staging: 4 threads/row (64B)
    const bf16* ag0 = Am + (size_t)(m0 + srow) * K + skch * 8;
    const bf16* ag1 = ag0 + (size_t)64 * K;
    const bf16* wg0 = Wm + (size_t)(n0 + srow) * K + skch * 8;
    const bf16* wg1 = wg0 + (size_t)64 * K;
    bf16* asl0 = As + tid * 8;  bf16* asl1 = As + 2048 + tid * 8;
    bf16* bsl0 = Bs + tid * 8;  bf16* bsl1 = Bs + 2048 + tid * 8;

    f32x4 acc[4][4];
    #pragma unroll
    for (int i = 0; i < 4; i++)
        #pragma unroll
        for (int j = 0; j < 4; j++) acc[i][j] = {0, 0, 0, 0};

    const int r0 = (w >> 1) * 64, c0 = (w & 1) * 64;

    for (int k0 = 0; k0 < K; k0 += 32) {
        __syncthreads();
        GLOAD_LDS(ag0 + k0, asl0);
        GLOAD_LDS(ag1 + k0, asl1);
        GLOAD_LDS(wg0 + k0, bsl0);
        GLOAD_LDS(wg1 + k0, bsl1);
        __syncthreads();
        bf16x8 af[4], bfv[4];
        #pragma unroll
        for (int it = 0; it < 4; it++)
            af[it] = *(const bf16x8*)(As + (r0 + it * 16 + row) * 32 + quad * 8);
        #pragma unroll
        for (int jt = 0; jt < 4; jt++)
            bfv[jt] = *(const bf16x8*)(Bs + (c0 + jt * 16 + row) * 32 + quad * 8);
        #pragma unroll
        for (int it = 0; it < 4; it++)
            #pragma unroll
            for (int jt = 0; jt < 4; jt++)
                acc[it][jt] = MFMA16(af[it], bfv[jt], acc[it][jt]);
    }

    #pragma unroll
    for (int it = 0; it < 4; it++)
    #pragma unroll
    for (int jt = 0; jt < 4; jt++)
    #pragma unroll
    for (int r = 0; r < 4; r++) {
        int m = m0 + r0 + it * 16 + quad * 4 + r;
        int n = n0 + c0 + jt * 16 + row;
        float val = acc[it][jt][r] + bias[n];
        int which = n >> 10, cc = n & 1023;
        if (which == 0) val *= QSCALE;
        bf16 bv = bfbits(f2bf(val));
        int h = cc >> 6, d = cc & 63;
        int b = m >> 11, t = m & 2047;
        int bh = b * Hn + h;
        if (which == 0)      qo[((size_t)bh * Tn + t) * Dn + d] = bv;
        else if (which == 1) ko[((size_t)bh * Tn + t) * Dn + d] = bv;
        else                 vo[((size_t)bh * 64 + (t >> 5)) * 2048 + (size_t)d * 32 + (t & 31)] = bv;
    }
}

// ---------------- Attention: shared-j, LDS-staged, merge-free -------------
// Item = (bh, 128-query block). 4 waves own 32 queries each; all iterate the
// same key-block j. K/V 4KB tiles staged via 8x global_load_lds (2 per wave),
// double-buffered (stage j+1 || compute j), tiles stored with chunk^=stripe&7
// swizzle via pre-swizzled global source. Per j-step per wave (all in regs):
// S^T = K*Q^T (4x mfma_32x32x16, lane=query col), exp2, lsum add-tree, P
// packed via v_cvt_pk_bf16_f32 + permlane32_swap into PV A-layout, PV 4x
// mfma. Epilogue: per-wave LDS transpose (reuse staging buf) -> coalesced O.
__global__ __launch_bounds__(256, 4) void attn_kernel(
    const bf16* __restrict__ qbp, const bf16* __restrict__ kbp,
    const bf16* __restrict__ vtb, bf16* __restrict__ ob,
    unsigned* __restrict__ counters)
{
    __shared__ __align__(128) bf16 SB[4][2048];   // [0..1]=K dbuf, [2..3]=V dbuf; epilogue: SB[w]=obuf
    __shared__ float lbufw[4][32];
    __shared__ unsigned item_s;
    const int tid  = threadIdx.x;
    const int lane = tid & 63;
    const int w    = tid >> 6;
    const int l31  = lane & 31, hl = lane >> 5;
    const int qid  = blockIdx.x & 7;             // round-robin XCD heuristic
    unsigned* ctr  = counters + qid * 32;        // 128B apart

    // staging: wave w stages sweep s=w of each tile (1KB each).
    // LDS slot (stripe, chunk16) holds source (stripe, chunk16 ^ (stripe&7)).
    const int stage_off = w * 1024 + (lane >> 3) * 128
                        + (((lane & 7) ^ ((lane >> 3) & 7)) << 4);
    const int kxor = (l31 & 7) << 4;             // K-tile read swizzle
    const int sxor = ((l31 >> 1) & 7) << 4;      // V-tile read swizzle

    for (;;) {
        if (tid == 0) item_s = atomicAdd(ctr, 1u);
        __syncthreads();
        const unsigned item = item_s;
        if (item >= 128u) break;
        const int qb8  = 15 - (int)(item >> 3);  // 128-query block, LPT
        const int bh   = qid * 8 + (int)(item & 7);
        const int jmax = qb8 * 4 + 3;
        const int qtw  = qb8 * 4 + w;            // this wave's diagonal block
        const int q0w  = qtw * 32;               // this wave's first query

        const bf16* Q  = qbp + (size_t)bh * Tn * Dn;
        const char* Kh = (const char*)(kbp + (size_t)bh * Tn * Dn);
        const char* Vh = (const char*)vtb + (size_t)bh * 262144;

        // Q fragments: B-operand of S^T, B[k=d][col=query l31]
        bf16x8 bQ[4];
        {
            const bf16* qp = Q + (size_t)(q0w + l31) * Dn + hl * 8;
            #pragma unroll
            for (int kf = 0; kf < 4; kf++) bQ[kf] = *(const bf16x8*)(qp + kf * 16);
        }

        f32x16 o2[2];
        o2[0] = {0,0,0,0,0,0,0,0,0,0,0,0,0,0,0,0};
        o2[1] = {0,0,0,0,0,0,0,0,0,0,0,0,0,0,0,0};
        float lsum = 0.f;

        // prologue: stage tile j=0
        GLOAD_LDS(Kh + stage_off, (char*)SB[0] + w * 1024);
        GLOAD_LDS(Vh + stage_off, (char*)SB[2] + w * 1024);
        __syncthreads();

        for (int j = 0; j <= jmax; j++) {
            const int cur = j & 1;
            if (j < jmax) {                      // stage tile j+1 (other buf)
                const int nb = cur ^ 1;
                GLOAD_LDS(Kh + (size_t)(j + 1) * 4096 + stage_off, (char*)SB[nb] + w * 1024);
                GLOAD_LDS(Vh + (size_t)(j + 1) * 4096 + stage_off, (char*)SB[2 + nb] + w * 1024);
            }
            if (j <= qtw) {
                const char* KB = (const char*)SB[cur];
                const char* VB = (const char*)SB[2 + cur];
                bf16x8 aK[4];
                #pragma unroll
                for (int kf = 0; kf < 4; kf++)
                    aK[kf] = *(const bf16x8*)(KB + l31 * 128 + ((((kf * 2 + hl)) << 4) ^ kxor));

                // S^T[key][query]: row = (r&3)+8*(r>>2)+4*hl, col = l31
                f32x16 s = {0,0,0,0,0,0,0,0,0,0,0,0,0,0,0,0};
                __builtin_amdgcn_s_setprio(1);
                s = MFMA32(aK[0], bQ[0], s);
                s = MFMA32(aK[1], bQ[1], s);
                s = MFMA32(aK[2], bQ[2], s);
                s = MFMA32(aK[3], bQ[3], s);
                __builtin_amdgcn_s_setprio(0);

                bf16x8 vf[4];                    // issue V reads; latency hides under softmax
                #pragma unroll
                for (int i2 = 0; i2 < 4; i2++) {
                    const int vh = i2 >> 1, kc = i2 & 1;
                    const int stripe = vh * 16 + (l31 >> 1);
                    vf[i2] = *(const bf16x8*)(VB + stripe * 128
                              + ((((l31 & 1) * 4 + kc * 2 + hl) << 4) ^ sxor));
                }

                float p[16];
                if (j == qtw) {                  // diagonal block: causal mask
                    #pragma unroll
                    for (int r = 0; r < 16; r++) {
                        const int krow = (r & 3) + 8 * (r >> 2) + 4 * hl;
                        float e = exp2f(s[r]);
                        p[r] = (krow > l31) ? 0.f : e;
                    }
                } else {
                    #pragma unroll
                    for (int r = 0; r < 16; r++) p[r] = exp2f(s[r]);
                }
                lsum += (((p[0]+p[1]) + (p[2]+p[3])) + ((p[4]+p[5]) + (p[6]+p[7])))
                      + (((p[8]+p[9]) + (p[10]+p[11])) + ((p[12]+p[13]) + (p[14]+p[15])));

                // pack P -> bf16 pairs, swap half-waves into A-operand layout
                unsigned a0 = cvtpk_bf16(p[0],  p[1]),  b0 = cvtpk_bf16(p[4],  p[5]);
                unsigned a1 = cvtpk_bf16(p[2],  p[3]),  b1 = cvtpk_bf16(p[6],  p[7]);
                unsigned a2 = cvtpk_bf16(p[8],  p[9]),  b2 = cvtpk_bf16(p[12], p[13]);
                unsigned a3 = cvtpk_bf16(p[10], p[11]), b3 = cvtpk_bf16(p[14], p[15]);
                permswap(a0, b0);
                permswap(a1, b1);
                permswap(a2, b2);
                permswap(a3, b3);
                const bf16x8 P0 = pack4(a0, a1, b0, b1);   // keys 0..15
                const bf16x8 P1 = pack4(a2, a3, b2, b3);   // keys 16..31

                __builtin_amdgcn_s_setprio(1);
                o2[0] = MFMA32(P0, vf[0], o2[0]);
                o2[0] = MFMA32(P1, vf[1], o2[0]);
                o2[1] = MFMA32(P0, vf[2], o2[1]);
                o2[1] = MFMA32(P1, vf[3], o2[1]);
                __builtin_amdgcn_s_setprio(0);
            }
            __syncthreads();
        }

        // ---- epilogue: per-wave, merge-free ----
        // lsum partner-sum across hl halves -> full denominator for query l31
        unsigned lsu = __float_as_uint(lsum), lsv = lsu;
        permswap(lsu, lsv);
        const float ltot = __uint_as_float(lsu) + __uint_as_float(lsv);
        if (hl == 0) lbufw[w][l31] = 1.0f / ltot;
        asm volatile("s_waitcnt lgkmcnt(0)" ::: "memory");

        // normalize + transpose via this wave's 4KB of staging LDS (swizzled)
        char* obl = (char*)SB[w];
        #pragma unroll
        for (int r = 0; r < 16; r++) {
            const int q  = (r & 3) + 8 * (r >> 2) + 4 * hl;
            const float rl = lbufw[w][q];
            const int qx = (q & 7) << 4;
            *(short*)(obl + q * 128 + ((2 * l31) ^ qx))      = f2bf(o2[0][r] * rl);
            *(short*)(obl + q * 128 + ((64 + 2 * l31) ^ qx)) = f2bf(o2[1][r] * rl);
        }
        asm volatile("s_waitcnt lgkmcnt(0)" ::: "memory");

        // coalesced output: lane pair (2 lanes per query row, 64B each)
        {
            const int q = lane >> 1, half = lane & 1;
            const int qx = (q & 7) << 4;
            const int b = bh >> 4, h = bh & 15;
            bf16* gdst = ob + ((size_t)(b * Tn + (q0w + q))) * Cn + h * Dn + half * 32;
            #pragma unroll
            for (int c = 0; c < 4; c++) {
                bf16x8 rv = *(const bf16x8*)(obl + q * 128 + (((half * 64) + c * 16) ^ qx));
                *(bf16x8*)(gdst + c * 8) = rv;
            }
        }
        __syncthreads();   // SB reuse guard (next item's staging)
    }
}

// ---------------- Output projection: 128x128 tile, fp32 out ---------------
__global__ __launch_bounds__(256) void proj_gemm128(
    const bf16* __restrict__ Am, const bf16* __restrict__ Wm,
    const float* __restrict__ bias, float* __restrict__ out)
{
    constexpr int K = 1024;
    __shared__ bf16 As[4096], Bs[4096];
    const int tid = threadIdx.x;
    const int lane = tid & 63, w = tid >> 6;
    const int row = lane & 15, quad = lane >> 4;
    const int tn = blockIdx.x % 8, tm = blockIdx.x / 8;
    const int m0 = tm * 128, n0 = tn * 128;

    const int srow = tid >> 2, skch = tid & 3;
    const bf16* ag0 = Am + (size_t)(m0 + srow) * K + skch * 8;
    const bf16* ag1 = ag0 + (size_t)64 * K;
    const bf16* wg0 = Wm + (size_t)(n0 + srow) * K + skch * 8;
    const bf16* wg1 = wg0 + (size_t)64 * K;
    bf16* asl0 = As + tid * 8;  bf16* asl1 = As + 2048 + tid * 8;
    bf16* bsl0 = Bs + tid * 8;  bf16* bsl1 = Bs + 2048 + tid * 8;

    f32x4 acc[4][4];
    #pragma unroll
    for (int i = 0; i < 4; i++)
        #pragma unroll
        for (int j = 0; j < 4; j++) acc[i][j] = {0, 0, 0, 0};

    const int r0 = (w >> 1) * 64, c0 = (w & 1) * 64;

    for (int k0 = 0; k0 < K; k0 += 32) {
        __syncthreads();
        GLOAD_LDS(ag0 + k0, asl0);
        GLOAD_LDS(ag1 + k0, asl1);
        GLOAD_LDS(wg0 + k0, bsl0);
        GLOAD_LDS(wg1 + k0, bsl1);
        __syncthreads();
        bf16x8 af[4], bfv[4];
        #pragma unroll
        for (int it = 0; it < 4; it++)
            af[it] = *(const bf16x8*)(As + (r0 + it * 16 + row) * 32 + quad * 8);
        #pragma unroll
        for (int jt = 0; jt < 4; jt++)
            bfv[jt] = *(const bf16x8*)(Bs + (c0 + jt * 16 + row) * 32 + quad * 8);
        #pragma unroll
        for (int it = 0; it < 4; it++)
            #pragma unroll
            for (int jt = 0; jt < 4; jt++)
                acc[it][jt] = MFMA16(af[it], bfv[jt], acc[it][jt]);
    }

    #pragma unroll
    for (int it = 0; it < 4; it++)
    #pragma unroll
    for (int jt = 0; jt < 4; jt++)
    #pragma unroll
    for (int r = 0; r < 4; r++) {
        int m = m0 + r0 + it * 16 + quad * 4 + r;
        int n = n0 + c0 + jt * 16 + row;
        out[(size_t)m * 1024 + n] = acc[it][jt][r] + bias[n];
    }
}

extern "C" void kernel_launch(void* const* d_in, const int* in_sizes, int n_in,
                              void* d_out, int out_size, void* d_ws, size_t ws_size,
                              hipStream_t stream) {
    const float* x      = (const float*)d_in[0];
    const float* w_attn = (const float*)d_in[1];
    const float* b_attn = (const float*)d_in[2];
    const float* w_proj = (const float*)d_in[3];
    const float* b_proj = (const float*)d_in[4];
    float* out = (float*)d_out;

    unsigned* counters = (unsigned*)d_ws;             // 8 counters @128B
    bf16* ws  = (bf16*)((char*)d_ws + 1024);
    bf16* xb  = ws;                                   // 8M elems
    bf16* wab = xb  + (size_t)8192 * 1024;            // 3M (contiguous after xb)
    bf16* wpb = wab + (size_t)3072 * 1024;            // 1M (contiguous after wab)
    bf16* q   = wpb + (size_t)1024 * 1024;            // 8M
    bf16* k   = q  + HT_ELEMS;
    bf16* vt  = k  + HT_ELEMS;                        // [bh][kblock][64][32]
    bf16* o   = vt + HT_ELEMS;

    hipMemsetAsync(counters, 0, 1024, stream);

    cast3_kernel<<<6144, 256, 0, stream>>>(x, w_attn, w_proj, xb);

    qkv_gemm128 <<<64 * 24, 256, 0, stream>>>(xb, wab, b_attn, q, k, vt);
    attn_kernel <<<1024, 256, 0, stream>>>(q, k, vt, o, counters);
    proj_gemm128<<<64 * 8, 256, 0, stream>>>(o, wpb, b_proj, out);
}

// Round 6
// 287.232 us; speedup vs baseline: 1.2110x; 1.0609x over previous
//
#include <hip/hip_runtime.h>
#include <hip/hip_bf16.h>

// Round 14 (= round 13 resubmit; prior run died to container-acquire failure,
// no counters). 2-phase (T3-minimum) pipeline for both GEMMs + T1 XCD swizzle.
// r12 counters: qkv dominates (108.6us, MfmaUtil 19%, VALU 14.5%, HBM 15%,
// occ 18%) -> latency-bound: the stage->vmcnt(0)+barrier->compute loop exposes
// full HBM latency every K-step with only ~2 waves/SIMD TLP. Fix: LDS double
// buffer (16->32KB), issue step t+1's 4 global_load_lds BEFORE computing step
// t, ONE barrier per step (its vmcnt(0) drain waits for the overlapped next-
// tile stage, not the current one). Barriers 64->33/block. XCD-aware swizzle
// (grid%8==0, bijective) gives A-panel L2 locality. attn/cast/epilogues
// frozen (r12 harness-verified).
// ws: [8 counters @128B = 1KB] | xb[8M] | wab[3M] | wpb[1M] | Q[8M] | K[8M] | Vt[8M] | O[8M]

typedef __hip_bfloat16 bf16;
typedef __attribute__((ext_vector_type(8))) short bf16x8;   // 8 bf16 / 4 VGPRs
typedef __attribute__((ext_vector_type(4))) float f32x4;
typedef __attribute__((ext_vector_type(16))) float f32x16;

#define MFMA16(a, b, c) __builtin_amdgcn_mfma_f32_16x16x32_bf16(a, b, c, 0, 0, 0)
#define MFMA32(a, b, c) __builtin_amdgcn_mfma_f32_32x32x16_bf16(a, b, c, 0, 0, 0)
#define GLOAD_LDS(g, l) __builtin_amdgcn_global_load_lds( \
    (const __attribute__((address_space(1))) void*)(g),    \
    (__attribute__((address_space(3))) void*)(l), 16, 0, 0)

constexpr int Bn = 4, Tn = 2048, Cn = 1024, Hn = 16, Dn = 64;
constexpr size_t HT_ELEMS = (size_t)64 * Tn * Dn;   // 8388608
constexpr float QSCALE = 0.18033688011112042f;      // 0.125 * log2(e)

__device__ __forceinline__ short f2bf(float f) {    // RNE fp32->bf16 (finite)
    unsigned u = __float_as_uint(f);
    return (short)((u + 0x7FFF + ((u >> 16) & 1)) >> 16);
}
__device__ __forceinline__ bf16 bfbits(short s) { bf16 b; __builtin_memcpy(&b, &s, 2); return b; }

__device__ __forceinline__ unsigned cvtpk_bf16(float lo, float hi) {
    unsigned r;
    asm("v_cvt_pk_bf16_f32 %0, %1, %2" : "=v"(r) : "v"(lo), "v"(hi));
    return r;
}
// swap(a,b): a' = {a_lo, b_lo}, b' = {a_hi, b_hi}  (32-lane halves)
__device__ __forceinline__ void permswap(unsigned& a, unsigned& b) {
#if __has_builtin(__builtin_amdgcn_permlane32_swap)
    auto r = __builtin_amdgcn_permlane32_swap(a, b, false, false);
    a = (unsigned)r[0]; b = (unsigned)r[1];
#else
    asm("v_permlane32_swap_b32 %0, %1" : "+v"(a), "+v"(b));
#endif
}
__device__ __forceinline__ bf16x8 pack4(unsigned w0, unsigned w1, unsigned w2, unsigned w3) {
    union { unsigned u[4]; bf16x8 v; } t;
    t.u[0] = w0; t.u[1] = w1; t.u[2] = w2; t.u[3] = w3;
    return t.v;
}

// ---------------- fp32 -> bf16 cast, all three inputs in one launch -------
__global__ __launch_bounds__(256) void cast3_kernel(
    const float* __restrict__ x, const float* __restrict__ wa,
    const float* __restrict__ wp, bf16* __restrict__ out)
{
    size_t i = (size_t)blockIdx.x * 256 + threadIdx.x;
    const float* src; size_t off;
    if (i < 1048576)      { src = x;  off = i; }
    else if (i < 1441792) { src = wa; off = i - 1048576; }
    else                  { src = wp; off = i - 1441792; }
    const float4* p = (const float4*)(src + off * 8);
    float4 a = p[0], b = p[1];
    bf16x8 r;
    r[0] = f2bf(a.x); r[1] = f2bf(a.y); r[2] = f2bf(a.z); r[3] = f2bf(a.w);
    r[4] = f2bf(b.x); r[5] = f2bf(b.y); r[6] = f2bf(b.z); r[7] = f2bf(b.w);
    *(bf16x8*)(out + i * 8) = r;
}

// ---------------- QKV GEMM: 128x128 tile, 2-phase LDS double-buffer ------
// V output layout: [bh][kblock=t>>5][d=64][tk=t&31]  (contiguous 4KB tiles)
__global__ __launch_bounds__(256) void qkv_gemm128(
    const bf16* __restrict__ Am, const bf16* __restrict__ Wm,
    const float* __restrict__ bias,
    bf16* __restrict__ qo, bf16* __restrict__ ko, bf16* __restrict__ vo)
{
    constexpr int K = 1024;
    __shared__ bf16 As[2][4096], Bs[2][4096];    // dbuf: 128 rows x 32 k
    const int tid = threadIdx.x;
    const int lane = tid & 63, w = tid >> 6;
    const int row = lane & 15, quad = lane >> 4;
    const unsigned bid = blockIdx.x;
    const unsigned swz = (bid & 7) * 192 + (bid >> 3);   // 1536/8, bijective
    const int tn = swz % 24, tm = swz / 24;
    const int m0 = tm * 128, n0 = tn * 128;

    const int srow = tid >> 2, skch = tid & 3;   // staging: 4 threads/row (64B)
    const bf16* ag0 = Am + (size_t)(m0 + srow) * K + skch * 8;
    const bf16* ag1 = ag0 + (size_t)64 * K;
    const bf16* wg0 = Wm + (size_t)(n0 + srow) * K + skch * 8;
    const bf16* wg1 = wg0 + (size_t)64 * K;

    f32x4 acc[4][4];
    #pragma unroll
    for (int i = 0; i < 4; i++)
        #pragma unroll
        for (int j = 0; j < 4; j++) acc[i][j] = {0, 0, 0, 0};

    const int r0 = (w >> 1) * 64, c0 = (w & 1) * 64;

    // prologue: stage k0=0 into buf 0
    GLOAD_LDS(ag0, As[0] + tid * 8);
    GLOAD_LDS(ag1, As[0] + 2048 + tid * 8);
    GLOAD_LDS(wg0, Bs[0] + tid * 8);
    GLOAD_LDS(wg1, Bs[0] + 2048 + tid * 8);
    __syncthreads();

    int cur = 0;
    for (int k0 = 0; k0 < K; k0 += 32) {
        const int nb = cur ^ 1;
        if (k0 + 32 < K) {                       // stage next tile (other buf)
            GLOAD_LDS(ag0 + k0 + 32, As[nb] + tid * 8);
            GLOAD_LDS(ag1 + k0 + 32, As[nb] + 2048 + tid * 8);
            GLOAD_LDS(wg0 + k0 + 32, Bs[nb] + tid * 8);
            GLOAD_LDS(wg1 + k0 + 32, Bs[nb] + 2048 + tid * 8);
        }
        const bf16* Ac = As[cur];
        const bf16* Bc = Bs[cur];
        bf16x8 af[4], bfv[4];
        #pragma unroll
        for (int it = 0; it < 4; it++)
            af[it] = *(const bf16x8*)(Ac + (r0 + it * 16 + row) * 32 + quad * 8);
        #pragma unroll
        for (int jt = 0; jt < 4; jt++)
            bfv[jt] = *(const bf16x8*)(Bc + (c0 + jt * 16 + row) * 32 + quad * 8);
        #pragma unroll
        for (int it = 0; it < 4; it++)
            #pragma unroll
            for (int jt = 0; jt < 4; jt++)
                acc[it][jt] = MFMA16(af[it], bfv[jt], acc[it][jt]);
        __syncthreads();                         // drains next-stage vmcnt + lgkm
        cur = nb;
    }

    #pragma unroll
    for (int it = 0; it < 4; it++)
    #pragma unroll
    for (int jt = 0; jt < 4; jt++)
    #pragma unroll
    for (int r = 0; r < 4; r++) {
        int m = m0 + r0 + it * 16 + quad * 4 + r;
        int n = n0 + c0 + jt * 16 + row;
        float val = acc[it][jt][r] + bias[n];
        int which = n >> 10, cc = n & 1023;
        if (which == 0) val *= QSCALE;
        bf16 bv = bfbits(f2bf(val));
        int h = cc >> 6, d = cc & 63;
        int b = m >> 11, t = m & 2047;
        int bh = b * Hn + h;
        if (which == 0)      qo[((size_t)bh * Tn + t) * Dn + d] = bv;
        else if (which == 1) ko[((size_t)bh * Tn + t) * Dn + d] = bv;
        else                 vo[((size_t)bh * 64 + (t >> 5)) * 2048 + (size_t)d * 32 + (t & 31)] = bv;
    }
}

// ---------------- Attention: shared-j, LDS-staged, merge-free -------------
// (r12 structure, harness-verified — frozen)
__global__ __launch_bounds__(256, 4) void attn_kernel(
    const bf16* __restrict__ qbp, const bf16* __restrict__ kbp,
    const bf16* __restrict__ vtb, bf16* __restrict__ ob,
    unsigned* __restrict__ counters)
{
    __shared__ __align__(128) bf16 SB[4][2048];   // [0..1]=K dbuf, [2..3]=V dbuf; epilogue: SB[w]=obuf
    __shared__ float lbufw[4][32];
    __shared__ unsigned item_s;
    const int tid  = threadIdx.x;
    const int lane = tid & 63;
    const int w    = tid >> 6;
    const int l31  = lane & 31, hl = lane >> 5;
    const int qid  = blockIdx.x & 7;             // round-robin XCD heuristic
    unsigned* ctr  = counters + qid * 32;        // 128B apart

    // staging: wave w stages sweep s=w of each tile (1KB each).
    // LDS slot (stripe, chunk16) holds source (stripe, chunk16 ^ (stripe&7)).
    const int stage_off = w * 1024 + (lane >> 3) * 128
                        + (((lane & 7) ^ ((lane >> 3) & 7)) << 4);
    const int kxor = (l31 & 7) << 4;             // K-tile read swizzle
    const int sxor = ((l31 >> 1) & 7) << 4;      // V-tile read swizzle

    for (;;) {
        if (tid == 0) item_s = atomicAdd(ctr, 1u);
        __syncthreads();
        const unsigned item = item_s;
        if (item >= 128u) break;
        const int qb8  = 15 - (int)(item >> 3);  // 128-query block, LPT
        const int bh   = qid * 8 + (int)(item & 7);
        const int jmax = qb8 * 4 + 3;
        const int qtw  = qb8 * 4 + w;            // this wave's diagonal block
        const int q0w  = qtw * 32;               // this wave's first query

        const bf16* Q  = qbp + (size_t)bh * Tn * Dn;
        const char* Kh = (const char*)(kbp + (size_t)bh * Tn * Dn);
        const char* Vh = (const char*)vtb + (size_t)bh * 262144;

        // Q fragments: B-operand of S^T, B[k=d][col=query l31]
        bf16x8 bQ[4];
        {
            const bf16* qp = Q + (size_t)(q0w + l31) * Dn + hl * 8;
            #pragma unroll
            for (int kf = 0; kf < 4; kf++) bQ[kf] = *(const bf16x8*)(qp + kf * 16);
        }

        f32x16 o2[2];
        o2[0] = {0,0,0,0,0,0,0,0,0,0,0,0,0,0,0,0};
        o2[1] = {0,0,0,0,0,0,0,0,0,0,0,0,0,0,0,0};
        float lsum = 0.f;

        // prologue: stage tile j=0
        GLOAD_LDS(Kh + stage_off, (char*)SB[0] + w * 1024);
        GLOAD_LDS(Vh + stage_off, (char*)SB[2] + w * 1024);
        __syncthreads();

        for (int j = 0; j <= jmax; j++) {
            const int cur = j & 1;
            if (j < jmax) {                      // stage tile j+1 (other buf)
                const int nb = cur ^ 1;
                GLOAD_LDS(Kh + (size_t)(j + 1) * 4096 + stage_off, (char*)SB[nb] + w * 1024);
                GLOAD_LDS(Vh + (size_t)(j + 1) * 4096 + stage_off, (char*)SB[2 + nb] + w * 1024);
            }
            if (j <= qtw) {
                const char* KB = (const char*)SB[cur];
                const char* VB = (const char*)SB[2 + cur];
                bf16x8 aK[4];
                #pragma unroll
                for (int kf = 0; kf < 4; kf++)
                    aK[kf] = *(const bf16x8*)(KB + l31 * 128 + ((((kf * 2 + hl)) << 4) ^ kxor));

                // S^T[key][query]: row = (r&3)+8*(r>>2)+4*hl, col = l31
                f32x16 s = {0,0,0,0,0,0,0,0,0,0,0,0,0,0,0,0};
                __builtin_amdgcn_s_setprio(1);
                s = MFMA32(aK[0], bQ[0], s);
                s = MFMA32(aK[1], bQ[1], s);
                s = MFMA32(aK[2], bQ[2], s);
                s = MFMA32(aK[3], bQ[3], s);
                __builtin_amdgcn_s_setprio(0);

                bf16x8 vf[4];                    // issue V reads; latency hides under softmax
                #pragma unroll
                for (int i2 = 0; i2 < 4; i2++) {
                    const int vh = i2 >> 1, kc = i2 & 1;
                    const int stripe = vh * 16 + (l31 >> 1);
                    vf[i2] = *(const bf16x8*)(VB + stripe * 128
                              + ((((l31 & 1) * 4 + kc * 2 + hl) << 4) ^ sxor));
                }

                float p[16];
                if (j == qtw) {                  // diagonal block: causal mask
                    #pragma unroll
                    for (int r = 0; r < 16; r++) {
                        const int krow = (r & 3) + 8 * (r >> 2) + 4 * hl;
                        float e = exp2f(s[r]);
                        p[r] = (krow > l31) ? 0.f : e;
                    }
                } else {
                    #pragma unroll
                    for (int r = 0; r < 16; r++) p[r] = exp2f(s[r]);
                }
                lsum += (((p[0]+p[1]) + (p[2]+p[3])) + ((p[4]+p[5]) + (p[6]+p[7])))
                      + (((p[8]+p[9]) + (p[10]+p[11])) + ((p[12]+p[13]) + (p[14]+p[15])));

                // pack P -> bf16 pairs, swap half-waves into A-operand layout
                unsigned a0 = cvtpk_bf16(p[0],  p[1]),  b0 = cvtpk_bf16(p[4],  p[5]);
                unsigned a1 = cvtpk_bf16(p[2],  p[3]),  b1 = cvtpk_bf16(p[6],  p[7]);
                unsigned a2 = cvtpk_bf16(p[8],  p[9]),  b2 = cvtpk_bf16(p[12], p[13]);
                unsigned a3 = cvtpk_bf16(p[10], p[11]), b3 = cvtpk_bf16(p[14], p[15]);
                permswap(a0, b0);
                permswap(a1, b1);
                permswap(a2, b2);
                permswap(a3, b3);
                const bf16x8 P0 = pack4(a0, a1, b0, b1);   // keys 0..15
                const bf16x8 P1 = pack4(a2, a3, b2, b3);   // keys 16..31

                __builtin_amdgcn_s_setprio(1);
                o2[0] = MFMA32(P0, vf[0], o2[0]);
                o2[0] = MFMA32(P1, vf[1], o2[0]);
                o2[1] = MFMA32(P0, vf[2], o2[1]);
                o2[1] = MFMA32(P1, vf[3], o2[1]);
                __builtin_amdgcn_s_setprio(0);
            }
            __syncthreads();
        }

        // ---- epilogue: per-wave, merge-free ----
        // lsum partner-sum across hl halves -> full denominator for query l31
        unsigned lsu = __float_as_uint(lsum), lsv = lsu;
        permswap(lsu, lsv);
        const float ltot = __uint_as_float(lsu) + __uint_as_float(lsv);
        if (hl == 0) lbufw[w][l31] = 1.0f / ltot;
        asm volatile("s_waitcnt lgkmcnt(0)" ::: "memory");

        // normalize + transpose via this wave's 4KB of staging LDS (swizzled)
        char* obl = (char*)SB[w];
        #pragma unroll
        for (int r = 0; r < 16; r++) {
            const int q  = (r & 3) + 8 * (r >> 2) + 4 * hl;
            const float rl = lbufw[w][q];
            const int qx = (q & 7) << 4;
            *(short*)(obl + q * 128 + ((2 * l31) ^ qx))      = f2bf(o2[0][r] * rl);
            *(short*)(obl + q * 128 + ((64 + 2 * l31) ^ qx)) = f2bf(o2[1][r] * rl);
        }
        asm volatile("s_waitcnt lgkmcnt(0)" ::: "memory");

        // coalesced output: lane pair (2 lanes per query row, 64B each)
        {
            const int q = lane >> 1, half = lane & 1;
            const int qx = (q & 7) << 4;
            const int b = bh >> 4, h = bh & 15;
            bf16* gdst = ob + ((size_t)(b * Tn + (q0w + q))) * Cn + h * Dn + half * 32;
            #pragma unroll
            for (int c = 0; c < 4; c++) {
                bf16x8 rv = *(const bf16x8*)(obl + q * 128 + (((half * 64) + c * 16) ^ qx));
                *(bf16x8*)(gdst + c * 8) = rv;
            }
        }
        __syncthreads();   // SB reuse guard (next item's staging)
    }
}

// ---------------- Output projection: 128x128 tile, 2-phase dbuf ----------
__global__ __launch_bounds__(256) void proj_gemm128(
    const bf16* __restrict__ Am, const bf16* __restrict__ Wm,
    const float* __restrict__ bias, float* __restrict__ out)
{
    constexpr int K = 1024;
    __shared__ bf16 As[2][4096], Bs[2][4096];
    const int tid = threadIdx.x;
    const int lane = tid & 63, w = tid >> 6;
    const int row = lane & 15, quad = lane >> 4;
    const unsigned bid = blockIdx.x;
    const unsigned swz = (bid & 7) * 64 + (bid >> 3);    // 512/8, bijective
    const int tn = swz % 8, tm = swz / 8;
    const int m0 = tm * 128, n0 = tn * 128;

    const int srow = tid >> 2, skch = tid & 3;
    const bf16* ag0 = Am + (size_t)(m0 + srow) * K + skch * 8;
    const bf16* ag1 = ag0 + (size_t)64 * K;
    const bf16* wg0 = Wm + (size_t)(n0 + srow) * K + skch * 8;
    const bf16* wg1 = wg0 + (size_t)64 * K;

    f32x4 acc[4][4];
    #pragma unroll
    for (int i = 0; i < 4; i++)
        #pragma unroll
        for (int j = 0; j < 4; j++) acc[i][j] = {0, 0, 0, 0};

    const int r0 = (w >> 1) * 64, c0 = (w & 1) * 64;

    GLOAD_LDS(ag0, As[0] + tid * 8);
    GLOAD_LDS(ag1, As[0] + 2048 + tid * 8);
    GLOAD_LDS(wg0, Bs[0] + tid * 8);
    GLOAD_LDS(wg1, Bs[0] + 2048 + tid * 8);
    __syncthreads();

    int cur = 0;
    for (int k0 = 0; k0 < K; k0 += 32) {
        const int nb = cur ^ 1;
        if (k0 + 32 < K) {
            GLOAD_LDS(ag0 + k0 + 32, As[nb] + tid * 8);
            GLOAD_LDS(ag1 + k0 + 32, As[nb] + 2048 + tid * 8);
            GLOAD_LDS(wg0 + k0 + 32, Bs[nb] + tid * 8);
            GLOAD_LDS(wg1 + k0 + 32, Bs[nb] + 2048 + tid * 8);
        }
        const bf16* Ac = As[cur];
        const bf16* Bc = Bs[cur];
        bf16x8 af[4], bfv[4];
        #pragma unroll
        for (int it = 0; it < 4; it++)
            af[it] = *(const bf16x8*)(Ac + (r0 + it * 16 + row) * 32 + quad * 8);
        #pragma unroll
        for (int jt = 0; jt < 4; jt++)
            bfv[jt] = *(const bf16x8*)(Bc + (c0 + jt * 16 + row) * 32 + quad * 8);
        #pragma unroll
        for (int it = 0; it < 4; it++)
            #pragma unroll
            for (int jt = 0; jt < 4; jt++)
                acc[it][jt] = MFMA16(af[it], bfv[jt], acc[it][jt]);
        __syncthreads();
        cur = nb;
    }

    #pragma unroll
    for (int it = 0; it < 4; it++)
    #pragma unroll
    for (int jt = 0; jt < 4; jt++)
    #pragma unroll
    for (int r = 0; r < 4; r++) {
        int m = m0 + r0 + it * 16 + quad * 4 + r;
        int n = n0 + c0 + jt * 16 + row;
        out[(size_t)m * 1024 + n] = acc[it][jt][r] + bias[n];
    }
}

extern "C" void kernel_launch(void* const* d_in, const int* in_sizes, int n_in,
                              void* d_out, int out_size, void* d_ws, size_t ws_size,
                              hipStream_t stream) {
    const float* x      = (const float*)d_in[0];
    const float* w_attn = (const float*)d_in[1];
    const float* b_attn = (const float*)d_in[2];
    const float* w_proj = (const float*)d_in[3];
    const float* b_proj = (const float*)d_in[4];
    float* out = (float*)d_out;

    unsigned* counters = (unsigned*)d_ws;             // 8 counters @128B
    bf16* ws  = (bf16*)((char*)d_ws + 1024);
    bf16* xb  = ws;                                   // 8M elems
    bf16* wab = xb  + (size_t)8192 * 1024;            // 3M (contiguous after xb)
    bf16* wpb = wab + (size_t)3072 * 1024;            // 1M (contiguous after wab)
    bf16* q   = wpb + (size_t)1024 * 1024;            // 8M
    bf16* k   = q  + HT_ELEMS;
    bf16* vt  = k  + HT_ELEMS;                        // [bh][kblock][64][32]
    bf16* o   = vt + HT_ELEMS;

    hipMemsetAsync(counters, 0, 1024, stream);

    cast3_kernel<<<6144, 256, 0, stream>>>(x, w_attn, w_proj, xb);

    qkv_gemm128 <<<64 * 24, 256, 0, stream>>>(xb, wab, b_attn, q, k, vt);
    attn_kernel <<<1024, 256, 0, stream>>>(q, k, vt, o, counters);
    proj_gemm128<<<64 * 8, 256, 0, stream>>>(o, wpb, b_proj, out);
}

// Round 7
// 280.593 us; speedup vs baseline: 1.2397x; 1.0237x over previous
//
#include <hip/hip_runtime.h>
#include <hip/hip_bf16.h>

// Round 15: balanced causal pairing for attention. r14 counters: attn is now
// the top kernel (130us) with Occupancy 23% and all pipes <31% busy ->
// load-imbalance-bound: grid 1024 with 128 items/qid queue = exactly 1 item
// per block (queue does nothing), item length prop. to qb8 (4..64 steps, 16x
// spread) -> random CU stacking, long tail. Fix: each block statically owns
// the PAIR (qb8=p, qb8=15-p): 68 steps for EVERY block (uniform). Grid 512
// (2 blocks/CU, 8 waves/CU constant). Queue/LPT/atomics/memset deleted.
// Inner body, staging, swizzles, epilogue byte-identical to r12/r14
// (harness-verified). GEMMs (2-phase dbuf + XCD swizzle) + cast frozen (r14).
// ws: [1KB pad] | xb[8M] | wab[3M] | wpb[1M] | Q[8M] | K[8M] | Vt[8M] | O[8M]

typedef __hip_bfloat16 bf16;
typedef __attribute__((ext_vector_type(8))) short bf16x8;   // 8 bf16 / 4 VGPRs
typedef __attribute__((ext_vector_type(4))) float f32x4;
typedef __attribute__((ext_vector_type(16))) float f32x16;

#define MFMA16(a, b, c) __builtin_amdgcn_mfma_f32_16x16x32_bf16(a, b, c, 0, 0, 0)
#define MFMA32(a, b, c) __builtin_amdgcn_mfma_f32_32x32x16_bf16(a, b, c, 0, 0, 0)
#define GLOAD_LDS(g, l) __builtin_amdgcn_global_load_lds( \
    (const __attribute__((address_space(1))) void*)(g),    \
    (__attribute__((address_space(3))) void*)(l), 16, 0, 0)

constexpr int Bn = 4, Tn = 2048, Cn = 1024, Hn = 16, Dn = 64;
constexpr size_t HT_ELEMS = (size_t)64 * Tn * Dn;   // 8388608
constexpr float QSCALE = 0.18033688011112042f;      // 0.125 * log2(e)

__device__ __forceinline__ short f2bf(float f) {    // RNE fp32->bf16 (finite)
    unsigned u = __float_as_uint(f);
    return (short)((u + 0x7FFF + ((u >> 16) & 1)) >> 16);
}
__device__ __forceinline__ bf16 bfbits(short s) { bf16 b; __builtin_memcpy(&b, &s, 2); return b; }

__device__ __forceinline__ unsigned cvtpk_bf16(float lo, float hi) {
    unsigned r;
    asm("v_cvt_pk_bf16_f32 %0, %1, %2" : "=v"(r) : "v"(lo), "v"(hi));
    return r;
}
// swap(a,b): a' = {a_lo, b_lo}, b' = {a_hi, b_hi}  (32-lane halves)
__device__ __forceinline__ void permswap(unsigned& a, unsigned& b) {
#if __has_builtin(__builtin_amdgcn_permlane32_swap)
    auto r = __builtin_amdgcn_permlane32_swap(a, b, false, false);
    a = (unsigned)r[0]; b = (unsigned)r[1];
#else
    asm("v_permlane32_swap_b32 %0, %1" : "+v"(a), "+v"(b));
#endif
}
__device__ __forceinline__ bf16x8 pack4(unsigned w0, unsigned w1, unsigned w2, unsigned w3) {
    union { unsigned u[4]; bf16x8 v; } t;
    t.u[0] = w0; t.u[1] = w1; t.u[2] = w2; t.u[3] = w3;
    return t.v;
}

// ---------------- fp32 -> bf16 cast, all three inputs in one launch -------
__global__ __launch_bounds__(256) void cast3_kernel(
    const float* __restrict__ x, const float* __restrict__ wa,
    const float* __restrict__ wp, bf16* __restrict__ out)
{
    size_t i = (size_t)blockIdx.x * 256 + threadIdx.x;
    const float* src; size_t off;
    if (i < 1048576)      { src = x;  off = i; }
    else if (i < 1441792) { src = wa; off = i - 1048576; }
    else                  { src = wp; off = i - 1441792; }
    const float4* p = (const float4*)(src + off * 8);
    float4 a = p[0], b = p[1];
    bf16x8 r;
    r[0] = f2bf(a.x); r[1] = f2bf(a.y); r[2] = f2bf(a.z); r[3] = f2bf(a.w);
    r[4] = f2bf(b.x); r[5] = f2bf(b.y); r[6] = f2bf(b.z); r[7] = f2bf(b.w);
    *(bf16x8*)(out + i * 8) = r;
}

// ---------------- QKV GEMM: 128x128 tile, 2-phase LDS double-buffer ------
// V output layout: [bh][kblock=t>>5][d=64][tk=t&31]  (contiguous 4KB tiles)
__global__ __launch_bounds__(256) void qkv_gemm128(
    const bf16* __restrict__ Am, const bf16* __restrict__ Wm,
    const float* __restrict__ bias,
    bf16* __restrict__ qo, bf16* __restrict__ ko, bf16* __restrict__ vo)
{
    constexpr int K = 1024;
    __shared__ bf16 As[2][4096], Bs[2][4096];    // dbuf: 128 rows x 32 k
    const int tid = threadIdx.x;
    const int lane = tid & 63, w = tid >> 6;
    const int row = lane & 15, quad = lane >> 4;
    const unsigned bid = blockIdx.x;
    const unsigned swz = (bid & 7) * 192 + (bid >> 3);   // 1536/8, bijective
    const int tn = swz % 24, tm = swz / 24;
    const int m0 = tm * 128, n0 = tn * 128;

    const int srow = tid >> 2, skch = tid & 3;   // staging: 4 threads/row (64B)
    const bf16* ag0 = Am + (size_t)(m0 + srow) * K + skch * 8;
    const bf16* ag1 = ag0 + (size_t)64 * K;
    const bf16* wg0 = Wm + (size_t)(n0 + srow) * K + skch * 8;
    const bf16* wg1 = wg0 + (size_t)64 * K;

    f32x4 acc[4][4];
    #pragma unroll
    for (int i = 0; i < 4; i++)
        #pragma unroll
        for (int j = 0; j < 4; j++) acc[i][j] = {0, 0, 0, 0};

    const int r0 = (w >> 1) * 64, c0 = (w & 1) * 64;

    // prologue: stage k0=0 into buf 0
    GLOAD_LDS(ag0, As[0] + tid * 8);
    GLOAD_LDS(ag1, As[0] + 2048 + tid * 8);
    GLOAD_LDS(wg0, Bs[0] + tid * 8);
    GLOAD_LDS(wg1, Bs[0] + 2048 + tid * 8);
    __syncthreads();

    int cur = 0;
    for (int k0 = 0; k0 < K; k0 += 32) {
        const int nb = cur ^ 1;
        if (k0 + 32 < K) {                       // stage next tile (other buf)
            GLOAD_LDS(ag0 + k0 + 32, As[nb] + tid * 8);
            GLOAD_LDS(ag1 + k0 + 32, As[nb] + 2048 + tid * 8);
            GLOAD_LDS(wg0 + k0 + 32, Bs[nb] + tid * 8);
            GLOAD_LDS(wg1 + k0 + 32, Bs[nb] + 2048 + tid * 8);
        }
        const bf16* Ac = As[cur];
        const bf16* Bc = Bs[cur];
        bf16x8 af[4], bfv[4];
        #pragma unroll
        for (int it = 0; it < 4; it++)
            af[it] = *(const bf16x8*)(Ac + (r0 + it * 16 + row) * 32 + quad * 8);
        #pragma unroll
        for (int jt = 0; jt < 4; jt++)
            bfv[jt] = *(const bf16x8*)(Bc + (c0 + jt * 16 + row) * 32 + quad * 8);
        #pragma unroll
        for (int it = 0; it < 4; it++)
            #pragma unroll
            for (int jt = 0; jt < 4; jt++)
                acc[it][jt] = MFMA16(af[it], bfv[jt], acc[it][jt]);
        __syncthreads();                         // drains next-stage vmcnt + lgkm
        cur = nb;
    }

    #pragma unroll
    for (int it = 0; it < 4; it++)
    #pragma unroll
    for (int jt = 0; jt < 4; jt++)
    #pragma unroll
    for (int r = 0; r < 4; r++) {
        int m = m0 + r0 + it * 16 + quad * 4 + r;
        int n = n0 + c0 + jt * 16 + row;
        float val = acc[it][jt][r] + bias[n];
        int which = n >> 10, cc = n & 1023;
        if (which == 0) val *= QSCALE;
        bf16 bv = bfbits(f2bf(val));
        int h = cc >> 6, d = cc & 63;
        int b = m >> 11, t = m & 2047;
        int bh = b * Hn + h;
        if (which == 0)      qo[((size_t)bh * Tn + t) * Dn + d] = bv;
        else if (which == 1) ko[((size_t)bh * Tn + t) * Dn + d] = bv;
        else                 vo[((size_t)bh * 64 + (t >> 5)) * 2048 + (size_t)d * 32 + (t & 31)] = bv;
    }
}

// ---------------- Attention: shared-j LDS staging, balanced pairs ---------
// Block (bid) statically owns (bh, pair p): processes query-blocks qb8=p and
// qb8=15-p sequentially -> 68 j-steps for every block (uniform, no queue).
// Per query-block: 4 waves own 32 queries each, iterate the same key-block j;
// K/V 4KB tiles staged via 8x global_load_lds, double-buffered, XOR-swizzled
// (chunk^=stripe&7). Per j-step per wave (all in regs): S^T = K*Q^T (4x
// mfma_32x32x16), exp2, lsum add-tree, cvt_pk+permlane32_swap -> PV A-frags,
// PV 4x mfma. Epilogue: per-wave LDS transpose -> coalesced O stores.
__global__ __launch_bounds__(256, 4) void attn_kernel(
    const bf16* __restrict__ qbp, const bf16* __restrict__ kbp,
    const bf16* __restrict__ vtb, bf16* __restrict__ ob)
{
    __shared__ __align__(128) bf16 SB[4][2048];   // [0..1]=K dbuf, [2..3]=V dbuf; epilogue: SB[w]=obuf
    __shared__ float lbufw[4][32];
    const int tid  = threadIdx.x;
    const int lane = tid & 63;
    const int w    = tid >> 6;
    const int l31  = lane & 31, hl = lane >> 5;
    const int bid  = blockIdx.x;
    const int qid  = bid & 7;                    // round-robin XCD heuristic
    const int idx  = bid >> 3;                   // 0..63
    const int bh   = qid * 8 + (idx & 7);
    const int pair = idx >> 3;                   // 0..7

    // staging: wave w stages sweep s=w of each tile (1KB each).
    // LDS slot (stripe, chunk16) holds source (stripe, chunk16 ^ (stripe&7)).
    const int stage_off = w * 1024 + (lane >> 3) * 128
                        + (((lane & 7) ^ ((lane >> 3) & 7)) << 4);
    const int kxor = (l31 & 7) << 4;             // K-tile read swizzle
    const int sxor = ((l31 >> 1) & 7) << 4;      // V-tile read swizzle

    const bf16* Q  = qbp + (size_t)bh * Tn * Dn;
    const char* Kh = (const char*)(kbp + (size_t)bh * Tn * Dn);
    const char* Vh = (const char*)vtb + (size_t)bh * 262144;

    #pragma unroll 1
    for (int sub = 0; sub < 2; sub++) {
        const int qb8  = sub ? (15 - pair) : pair;
        const int jmax = qb8 * 4 + 3;
        const int qtw  = qb8 * 4 + w;            // this wave's diagonal block
        const int q0w  = qtw * 32;               // this wave's first query

        // Q fragments: B-operand of S^T, B[k=d][col=query l31]
        bf16x8 bQ[4];
        {
            const bf16* qp = Q + (size_t)(q0w + l31) * Dn + hl * 8;
            #pragma unroll
            for (int kf = 0; kf < 4; kf++) bQ[kf] = *(const bf16x8*)(qp + kf * 16);
        }

        f32x16 o2[2];
        o2[0] = {0,0,0,0,0,0,0,0,0,0,0,0,0,0,0,0};
        o2[1] = {0,0,0,0,0,0,0,0,0,0,0,0,0,0,0,0};
        float lsum = 0.f;

        // prologue: stage tile j=0
        GLOAD_LDS(Kh + stage_off, (char*)SB[0] + w * 1024);
        GLOAD_LDS(Vh + stage_off, (char*)SB[2] + w * 1024);
        __syncthreads();

        for (int j = 0; j <= jmax; j++) {
            const int cur = j & 1;
            if (j < jmax) {                      // stage tile j+1 (other buf)
                const int nb = cur ^ 1;
                GLOAD_LDS(Kh + (size_t)(j + 1) * 4096 + stage_off, (char*)SB[nb] + w * 1024);
                GLOAD_LDS(Vh + (size_t)(j + 1) * 4096 + stage_off, (char*)SB[2 + nb] + w * 1024);
            }
            if (j <= qtw) {
                const char* KB = (const char*)SB[cur];
                const char* VB = (const char*)SB[2 + cur];
                bf16x8 aK[4];
                #pragma unroll
                for (int kf = 0; kf < 4; kf++)
                    aK[kf] = *(const bf16x8*)(KB + l31 * 128 + ((((kf * 2 + hl)) << 4) ^ kxor));

                // S^T[key][query]: row = (r&3)+8*(r>>2)+4*hl, col = l31
                f32x16 s = {0,0,0,0,0,0,0,0,0,0,0,0,0,0,0,0};
                __builtin_amdgcn_s_setprio(1);
                s = MFMA32(aK[0], bQ[0], s);
                s = MFMA32(aK[1], bQ[1], s);
                s = MFMA32(aK[2], bQ[2], s);
                s = MFMA32(aK[3], bQ[3], s);
                __builtin_amdgcn_s_setprio(0);

                bf16x8 vf[4];                    // issue V reads; latency hides under softmax
                #pragma unroll
                for (int i2 = 0; i2 < 4; i2++) {
                    const int vh = i2 >> 1, kc = i2 & 1;
                    const int stripe = vh * 16 + (l31 >> 1);
                    vf[i2] = *(const bf16x8*)(VB + stripe * 128
                              + ((((l31 & 1) * 4 + kc * 2 + hl) << 4) ^ sxor));
                }

                float p[16];
                if (j == qtw) {                  // diagonal block: causal mask
                    #pragma unroll
                    for (int r = 0; r < 16; r++) {
                        const int krow = (r & 3) + 8 * (r >> 2) + 4 * hl;
                        float e = exp2f(s[r]);
                        p[r] = (krow > l31) ? 0.f : e;
                    }
                } else {
                    #pragma unroll
                    for (int r = 0; r < 16; r++) p[r] = exp2f(s[r]);
                }
                lsum += (((p[0]+p[1]) + (p[2]+p[3])) + ((p[4]+p[5]) + (p[6]+p[7])))
                      + (((p[8]+p[9]) + (p[10]+p[11])) + ((p[12]+p[13]) + (p[14]+p[15])));

                // pack P -> bf16 pairs, swap half-waves into A-operand layout
                unsigned a0 = cvtpk_bf16(p[0],  p[1]),  b0 = cvtpk_bf16(p[4],  p[5]);
                unsigned a1 = cvtpk_bf16(p[2],  p[3]),  b1 = cvtpk_bf16(p[6],  p[7]);
                unsigned a2 = cvtpk_bf16(p[8],  p[9]),  b2 = cvtpk_bf16(p[12], p[13]);
                unsigned a3 = cvtpk_bf16(p[10], p[11]), b3 = cvtpk_bf16(p[14], p[15]);
                permswap(a0, b0);
                permswap(a1, b1);
                permswap(a2, b2);
                permswap(a3, b3);
                const bf16x8 P0 = pack4(a0, a1, b0, b1);   // keys 0..15
                const bf16x8 P1 = pack4(a2, a3, b2, b3);   // keys 16..31

                __builtin_amdgcn_s_setprio(1);
                o2[0] = MFMA32(P0, vf[0], o2[0]);
                o2[0] = MFMA32(P1, vf[1], o2[0]);
                o2[1] = MFMA32(P0, vf[2], o2[1]);
                o2[1] = MFMA32(P1, vf[3], o2[1]);
                __builtin_amdgcn_s_setprio(0);
            }
            __syncthreads();
        }

        // ---- epilogue: per-wave, merge-free ----
        // lsum partner-sum across hl halves -> full denominator for query l31
        unsigned lsu = __float_as_uint(lsum), lsv = lsu;
        permswap(lsu, lsv);
        const float ltot = __uint_as_float(lsu) + __uint_as_float(lsv);
        if (hl == 0) lbufw[w][l31] = 1.0f / ltot;
        asm volatile("s_waitcnt lgkmcnt(0)" ::: "memory");

        // normalize + transpose via this wave's 4KB of staging LDS (swizzled)
        char* obl = (char*)SB[w];
        #pragma unroll
        for (int r = 0; r < 16; r++) {
            const int q  = (r & 3) + 8 * (r >> 2) + 4 * hl;
            const float rl = lbufw[w][q];
            const int qx = (q & 7) << 4;
            *(short*)(obl + q * 128 + ((2 * l31) ^ qx))      = f2bf(o2[0][r] * rl);
            *(short*)(obl + q * 128 + ((64 + 2 * l31) ^ qx)) = f2bf(o2[1][r] * rl);
        }
        asm volatile("s_waitcnt lgkmcnt(0)" ::: "memory");

        // coalesced output: lane pair (2 lanes per query row, 64B each)
        {
            const int q = lane >> 1, half = lane & 1;
            const int qx = (q & 7) << 4;
            const int b = bh >> 4, h = bh & 15;
            bf16* gdst = ob + ((size_t)(b * Tn + (q0w + q))) * Cn + h * Dn + half * 32;
            #pragma unroll
            for (int c = 0; c < 4; c++) {
                bf16x8 rv = *(const bf16x8*)(obl + q * 128 + (((half * 64) + c * 16) ^ qx));
                *(bf16x8*)(gdst + c * 8) = rv;
            }
        }
        __syncthreads();   // SB reuse guard (next sub-item's staging)
    }
}

// ---------------- Output projection: 128x128 tile, 2-phase dbuf ----------
__global__ __launch_bounds__(256) void proj_gemm128(
    const bf16* __restrict__ Am, const bf16* __restrict__ Wm,
    const float* __restrict__ bias, float* __restrict__ out)
{
    constexpr int K = 1024;
    __shared__ bf16 As[2][4096], Bs[2][4096];
    const int tid = threadIdx.x;
    const int lane = tid & 63, w = tid >> 6;
    const int row = lane & 15, quad = lane >> 4;
    const unsigned bid = blockIdx.x;
    const unsigned swz = (bid & 7) * 64 + (bid >> 3);    // 512/8, bijective
    const int tn = swz % 8, tm = swz / 8;
    const int m0 = tm * 128, n0 = tn * 128;

    const int srow = tid >> 2, skch = tid & 3;
    const bf16* ag0 = Am + (size_t)(m0 + srow) * K + skch * 8;
    const bf16* ag1 = ag0 + (size_t)64 * K;
    const bf16* wg0 = Wm + (size_t)(n0 + srow) * K + skch * 8;
    const bf16* wg1 = wg0 + (size_t)64 * K;

    f32x4 acc[4][4];
    #pragma unroll
    for (int i = 0; i < 4; i++)
        #pragma unroll
        for (int j = 0; j < 4; j++) acc[i][j] = {0, 0, 0, 0};

    const int r0 = (w >> 1) * 64, c0 = (w & 1) * 64;

    GLOAD_LDS(ag0, As[0] + tid * 8);
    GLOAD_LDS(ag1, As[0] + 2048 + tid * 8);
    GLOAD_LDS(wg0, Bs[0] + tid * 8);
    GLOAD_LDS(wg1, Bs[0] + 2048 + tid * 8);
    __syncthreads();

    int cur = 0;
    for (int k0 = 0; k0 < K; k0 += 32) {
        const int nb = cur ^ 1;
        if (k0 + 32 < K) {
            GLOAD_LDS(ag0 + k0 + 32, As[nb] + tid * 8);
            GLOAD_LDS(ag1 + k0 + 32, As[nb] + 2048 + tid * 8);
            GLOAD_LDS(wg0 + k0 + 32, Bs[nb] + tid * 8);
            GLOAD_LDS(wg1 + k0 + 32, Bs[nb] + 2048 + tid * 8);
        }
        const bf16* Ac = As[cur];
        const bf16* Bc = Bs[cur];
        bf16x8 af[4], bfv[4];
        #pragma unroll
        for (int it = 0; it < 4; it++)
            af[it] = *(const bf16x8*)(Ac + (r0 + it * 16 + row) * 32 + quad * 8);
        #pragma unroll
        for (int jt = 0; jt < 4; jt++)
            bfv[jt] = *(const bf16x8*)(Bc + (c0 + jt * 16 + row) * 32 + quad * 8);
        #pragma unroll
        for (int it = 0; it < 4; it++)
            #pragma unroll
            for (int jt = 0; jt < 4; jt++)
                acc[it][jt] = MFMA16(af[it], bfv[jt], acc[it][jt]);
        __syncthreads();
        cur = nb;
    }

    #pragma unroll
    for (int it = 0; it < 4; it++)
    #pragma unroll
    for (int jt = 0; jt < 4; jt++)
    #pragma unroll
    for (int r = 0; r < 4; r++) {
        int m = m0 + r0 + it * 16 + quad * 4 + r;
        int n = n0 + c0 + jt * 16 + row;
        out[(size_t)m * 1024 + n] = acc[it][jt][r] + bias[n];
    }
}

extern "C" void kernel_launch(void* const* d_in, const int* in_sizes, int n_in,
                              void* d_out, int out_size, void* d_ws, size_t ws_size,
                              hipStream_t stream) {
    const float* x      = (const float*)d_in[0];
    const float* w_attn = (const float*)d_in[1];
    const float* b_attn = (const float*)d_in[2];
    const float* w_proj = (const float*)d_in[3];
    const float* b_proj = (const float*)d_in[4];
    float* out = (float*)d_out;

    bf16* ws  = (bf16*)((char*)d_ws + 1024);          // keep r14 layout offsets
    bf16* xb  = ws;                                   // 8M elems
    bf16* wab = xb  + (size_t)8192 * 1024;            // 3M (contiguous after xb)
    bf16* wpb = wab + (size_t)3072 * 1024;            // 1M (contiguous after wab)
    bf16* q   = wpb + (size_t)1024 * 1024;            // 8M
    bf16* k   = q  + HT_ELEMS;
    bf16* vt  = k  + HT_ELEMS;                        // [bh][kblock][64][32]
    bf16* o   = vt + HT_ELEMS;

    cast3_kernel<<<6144, 256, 0, stream>>>(x, w_attn, w_proj, xb);

    qkv_gemm128 <<<64 * 24, 256, 0, stream>>>(xb, wab, b_attn, q, k, vt);
    attn_kernel <<<512, 256, 0, stream>>>(q, k, vt, o);
    proj_gemm128<<<64 * 8, 256, 0, stream>>>(o, wpb, b_proj, out);
}